// Round 1
// baseline (343.580 us; speedup 1.0000x reference)
//
#include <hip/hip_runtime.h>
#include <stdint.h>

typedef unsigned long long u64;
typedef unsigned int u32;

#define N_ANCH 36864
#define WGRID 64
#define A_PER 9
#define KTOP 6000
#define NOUT 300
#define SORTN 8192

// Base anchors from py-faster-rcnn generate_anchors (scales 8,16,32; ratios .5,1,2), all exact integers.
__constant__ float c_ax1[9] = {-84.f,-176.f,-360.f,-56.f,-120.f,-248.f,-36.f,-80.f,-168.f};
__constant__ float c_ay1[9] = {-40.f,-88.f,-184.f,-56.f,-120.f,-248.f,-80.f,-168.f,-344.f};
__constant__ float c_aw[9]  = {184.f,368.f,736.f,128.f,256.f,512.f,88.f,176.f,352.f};
__constant__ float c_ah[9]  = {96.f,192.f,384.f,128.f,256.f,512.f,176.f,352.f,704.f};

__global__ void proposal_kernel(const float* __restrict__ cls,
                                const float* __restrict__ dlt,
                                u64* __restrict__ keys,
                                float4* __restrict__ boxes) {
    int i = blockIdx.x * blockDim.x + threadIdx.x;
    if (i >= N_ANCH) return;
    int a  = i % A_PER;
    int hw = i / A_PER;
    int wx = hw % WGRID;
    int hy = hw / WGRID;

    // softmax over 2 logits, class-1 prob (matches jax.nn.softmax: subtract max)
    float l0 = cls[hw * 18 + 2 * a];
    float l1 = cls[hw * 18 + 2 * a + 1];
    float m  = fmaxf(l0, l1);
    float e0 = expf(l0 - m), e1 = expf(l1 - m);
    float s  = e1 / (e0 + e1);

    const float* d = dlt + hw * 36 + 4 * a;
    float dx = d[0], dy = d[1], dw = d[2], dh = d[3];
    float aw = c_aw[a], ah = c_ah[a];
    float axc = (c_ax1[a] + 16.f * (float)wx) + 0.5f * aw;
    float ayc = (c_ay1[a] + 16.f * (float)hy) + 0.5f * ah;

    float pxc = dx * aw + axc;
    float pyc = dy * ah + ayc;
    float pw  = expf(dw) * aw;
    float ph  = expf(dh) * ah;
    float x1 = pxc - 0.5f * pw, y1 = pyc - 0.5f * ph;
    float x2 = pxc + 0.5f * pw, y2 = pyc + 0.5f * ph;
    x1 = fminf(fmaxf(x1, 0.f), 1023.f);
    x2 = fminf(fmaxf(x2, 0.f), 1023.f);
    y1 = fminf(fmaxf(y1, 0.f), 1023.f);
    y2 = fminf(fmaxf(y2, 0.f), 1023.f);
    bool valid = ((x2 - x1 + 1.f) >= 16.f) && ((y2 - y1 + 1.f) >= 16.f);
    float sc = valid ? s : -__builtin_huge_valf();

    // order-preserving float->uint; key = (ord(score)<<32) | ~index  (desc score, asc index)
    u32 sb  = __float_as_uint(sc);
    u32 ord = (sb & 0x80000000u) ? ~sb : (sb | 0x80000000u);
    keys[i]  = ((u64)ord << 32) | (u32)(~(u32)i);
    boxes[i] = make_float4(x1, y1, x2, y2);
}

// Single block: exact radix-select of top-6000 keys, compact, bitonic sort (desc),
// compute V = #finite-score entries among top-6000, gather top boxes.
__global__ __launch_bounds__(1024) void select_kernel(const u64* __restrict__ keys,
                                                      const float4* __restrict__ boxes,
                                                      float4* __restrict__ topBoxes,
                                                      int* __restrict__ gV) {
    __shared__ u64 sbuf[SORTN];               // 64 KB, multi-purpose
    u32* shist = (u32*)sbuf;                  // [0..255] histogram (select phase)
    u32* ssc   = ((u32*)sbuf) + 16000;        // scalars (select phase; clobbered later by pad - OK)
    u32* scnt  = ((u32*)sbuf) + 16008;        // compact counter
    const int tid = threadIdx.x;
    const int NT = 1024;

    u64 mask = 0, prefix = 0;
    int need = KTOP;
    for (int d = 7; d >= 0; --d) {
        int shift = d * 8;
        for (int b = tid; b < 256; b += NT) shist[b] = 0;
        __syncthreads();
        for (int i = tid; i < N_ANCH; i += NT) {
            u64 k = keys[i];
            if ((k & mask) == prefix)
                atomicAdd(&shist[(u32)((k >> shift) & 0xFF)], 1u);
        }
        __syncthreads();
        if (tid == 0) {
            int cum = 0, sel = 0, cnt_sel = 0;
            for (int b = 255; b >= 0; --b) {
                int h = (int)shist[b];
                cum += h;
                if (cum >= need) { sel = b; cnt_sel = h; break; }
            }
            ssc[0] = (u32)sel;
            ssc[1] = (u32)(need - (cum - cnt_sel));  // new need
            ssc[2] = (u32)cnt_sel;
        }
        __syncthreads();
        int sel      = (int)ssc[0];
        int need_new = (int)ssc[1];
        int cnt_sel  = (int)ssc[2];
        prefix |= ((u64)(u32)sel) << shift;
        mask   |= (0xFFULL << shift);
        need = need_new;
        if (cnt_sel == need) break;   // uniform: all keys matching prefix are in top-K
    }
    // compact: keys unique => exactly KTOP satisfy (k & mask) >= prefix
    if (tid == 0) *scnt = 0;
    __syncthreads();
    for (int i = tid; i < N_ANCH; i += NT) {
        u64 k = keys[i];
        if ((k & mask) >= prefix) {
            u32 pos = atomicAdd(scnt, 1u);
            sbuf[pos] = k;
        }
    }
    __syncthreads();
    for (int i = KTOP + tid; i < SORTN; i += NT) sbuf[i] = 0;  // pad (sorts last)
    __syncthreads();
    // bitonic sort, descending
    for (int k = 2; k <= SORTN; k <<= 1) {
        for (int j = k >> 1; j > 0; j >>= 1) {
            for (int i = tid; i < SORTN; i += NT) {
                int ixj = i ^ j;
                if (ixj > i) {
                    u64 va = sbuf[i], vb = sbuf[ixj];
                    bool up = ((i & k) == 0);          // descending overall
                    if (up ? (va < vb) : (va > vb)) { sbuf[i] = vb; sbuf[ixj] = va; }
                }
            }
            __syncthreads();
        }
    }
    // V = count of finite-score keys in top-KTOP (finite <=> top bit set); sorted => binary search
    if (tid == 0) {
        int lo = 0, hi = KTOP;
        while (lo < hi) {
            int mid = (lo + hi) >> 1;
            if (sbuf[mid] & 0x8000000000000000ULL) lo = mid + 1; else hi = mid;
        }
        gV[0] = lo;
    }
    for (int r = tid; r < KTOP; r += NT) {
        u64 k = sbuf[r];
        int i = (int)(~(u32)k);
        topBoxes[r] = boxes[i];
    }
}

__device__ __forceinline__ bool iou_gt(float4 a, float areaA, float4 b, float areaB) {
    float ix1 = fmaxf(a.x, b.x), iy1 = fmaxf(a.y, b.y);
    float ix2 = fminf(a.z, b.z), iy2 = fminf(a.w, b.w);
    float iw = fmaxf(ix2 - ix1 + 1.0f, 0.0f);
    float ih = fmaxf(iy2 - iy1 + 1.0f, 0.0f);
    float inter = iw * ih;
    float iou = inter / (areaA + areaB - inter);
    return iou > 0.7f;
}

// Single block, 256 threads: chunked greedy NMS over sorted boxes with early exit at 300 kept,
// then write the 300x5 output blob (with the reference's -inf/suppressed tie-break fallback).
__global__ __launch_bounds__(256) void nms_out_kernel(const float4* __restrict__ topBoxes,
                                                      const int* __restrict__ gV,
                                                      float* __restrict__ out) {
    __shared__ float4 cbox[64];
    __shared__ float  carea[64];
    __shared__ float4 kbox[NOUT];
    __shared__ float  karea[NOUT];
    __shared__ u64 intra[64];
    __shared__ u64 supg[4];
    __shared__ u64 keepw[94];
    __shared__ u64 s_kb;
    __shared__ int s_nkept, s_old, s_V;

    const int tid = threadIdx.x;
    if (tid == 0) { s_nkept = 0; s_V = gV[0]; }
    if (tid < 94) keepw[tid] = 0;
    __syncthreads();
    const int V = s_V;   // only ranks < V matter for the output

    for (int c = 0; c < 94; ++c) {
        int base = c * 64;
        if (base >= V || s_nkept >= NOUT) break;
        int csz = min(64, V - base);
        if (tid < csz) {
            float4 b = topBoxes[base + tid];
            cbox[tid]  = b;
            carea[tid] = (b.z - b.x + 1.f) * (b.w - b.y + 1.f);
        }
        __syncthreads();
        // suppressed-by-kept: wave g tests kept indices k ≡ g (mod 4) for chunk box = lane
        int lane = tid & 63, g = tid >> 6;
        bool sup = false;
        int nk = s_nkept;
        if (lane < csz) {
            float4 bb = cbox[lane]; float ab = carea[lane];
            for (int k = g; k < nk; k += 4) {
                if (iou_gt(bb, ab, kbox[k], karea[k])) { sup = true; break; }
            }
        }
        u64 bal = __ballot(sup);
        if (lane == 0) supg[g] = bal;
        __syncthreads();
        // intra-chunk pair masks: bit j of intra[i] = (j>i && IoU>thresh)
        if (tid < csz) {
            float4 bb = cbox[tid]; float ab = carea[tid];
            u64 m = 0;
            for (int j = tid + 1; j < csz; ++j)
                if (iou_gt(bb, ab, cbox[j], carea[j])) m |= (1ULL << j);
            intra[tid] = m;
        }
        __syncthreads();
        if (tid == 0) {
            u64 alive = ~(supg[0] | supg[1] | supg[2] | supg[3]);
            if (csz < 64) alive &= ((1ULL << csz) - 1ULL);
            u64 cand = alive, keptbits = 0;
            int nk2 = s_nkept;
            while (cand && nk2 < NOUT) {
                int b = __builtin_ctzll(cand);
                cand &= cand - 1;
                keptbits |= (1ULL << b);
                ++nk2;
                cand &= ~intra[b];
            }
            keepw[c] = keptbits;
            s_kb  = keptbits;
            s_old = s_nkept;
            s_nkept = nk2;
        }
        __syncthreads();
        // parallel append of kept boxes in chunk order
        u64 kb = s_kb;
        int old = s_old;
        if (tid < 64 && ((kb >> tid) & 1ULL)) {
            int pos = old + __popcll(kb & ((1ULL << tid) - 1ULL));
            kbox[pos]  = cbox[tid];
            karea[pos] = carea[tid];
        }
        __syncthreads();
    }

    int n1 = s_nkept;  // <= 300 kept with finite score, in score-desc order
    for (int r = tid; r < n1; r += 256) {
        float4 b = kbox[r];
        out[r * 5 + 0] = 0.f;
        out[r * 5 + 1] = b.x; out[r * 5 + 2] = b.y;
        out[r * 5 + 3] = b.z; out[r * 5 + 4] = b.w;
    }
    // fallback: fewer than 300 kept -> remaining slots are -inf ties, ascending rank order
    if (n1 < NOUT && tid == 0) {
        int fill = n1;
        for (int r = 0; r < KTOP && fill < NOUT; ++r) {
            bool g1 = (r < V) && ((keepw[r >> 6] >> (r & 63)) & 1ULL);
            if (!g1) {
                float4 b = topBoxes[r];
                out[fill * 5 + 0] = 0.f;
                out[fill * 5 + 1] = b.x; out[fill * 5 + 2] = b.y;
                out[fill * 5 + 3] = b.z; out[fill * 5 + 4] = b.w;
                ++fill;
            }
        }
    }
}

extern "C" void kernel_launch(void* const* d_in, const int* in_sizes, int n_in,
                              void* d_out, int out_size, void* d_ws, size_t ws_size,
                              hipStream_t stream) {
    const float* cls = (const float*)d_in[0];   // (1,64,64,18) f32
    const float* dlt = (const float*)d_in[1];   // (1,64,64,36) f32
    float* out = (float*)d_out;                 // 300x5 f32
    char* ws = (char*)d_ws;
    u64*    keys     = (u64*)(ws);                               // 36864*8  = 294912 B
    float4* boxes    = (float4*)(ws + 294912);                   // 36864*16 = 589824 B
    float4* topBoxes = (float4*)(ws + 294912 + 589824);          // 6000*16  =  96000 B
    int*    gV       = (int*)(ws + 294912 + 589824 + 96000);

    proposal_kernel<<<(N_ANCH + 255) / 256, 256, 0, stream>>>(cls, dlt, keys, boxes);
    select_kernel<<<1, 1024, 0, stream>>>(keys, boxes, topBoxes, gV);
    nms_out_kernel<<<1, 256, 0, stream>>>(topBoxes, gV, out);
}